// Round 1
// 2777.799 us; speedup vs baseline: 1.4771x; 1.4771x over previous
//
#include <hip/hip_runtime.h>
#include <math.h>

#define NB   2
#define SEQ  1024
#define TOK  2048      // NB*SEQ
#define DEM  1024
#define NH   16
#define DH   64
#define FFD  4096
#define NL   6
#define VOC  32000

typedef __bf16 bf16x8 __attribute__((ext_vector_type(8)));
typedef float  f32x4  __attribute__((ext_vector_type(4)));
typedef const __attribute__((address_space(1))) void gvoid_t;
typedef __attribute__((address_space(3)))       void lvoid_t;

// XOR-swizzle for [R][64] bf16 LDS planes, 16B-chunk granularity.
// element (r, c8) with c8 % 8 == 0 lives at this bf16 index.
__device__ __forceinline__ int swz8(int r, int c8) {
  return r * 64 + (((c8 >> 3) ^ (r & 7)) << 3);
}

// ---------------------------------------------------------------------------
// Embedding + positional encoding: x[t,i] = emb[ids[t],i]*32 + pe(s,i)
// ---------------------------------------------------------------------------
__global__ __launch_bounds__(256) void k_embed(const int* __restrict__ ids,
    const float* __restrict__ emb, float* __restrict__ x)
{
  int t = blockIdx.x;
  int s = t & (SEQ - 1);
  int id = ids[t];
  int d0 = threadIdx.x * 4;
  const float ln10000 = 9.210340371976184f;
  #pragma unroll
  for (int j = 0; j < 4; j++) {
    int i = d0 + j;
    float inv = expf(-(2.0f * (float)i / (float)DEM) * ln10000);
    float ang = (float)s * inv;
    float pe = ((i & 1) == 0) ? sinf(ang) : cosf(ang);
    x[(size_t)t * DEM + i] = emb[(size_t)id * DEM + i] * 32.0f + pe;
  }
}

// ---------------------------------------------------------------------------
// Fused q/k/v per-head projection (3 phases through shared LDS, 1 dispatch).
// q,k outputs: bf16 hi/lo planes [TOK][DEM] (split-bf16 for exact-ish QK^T).
// v output: bf16, TRANSPOSED to Vt[DEM][TOK] so attention PV stages linearly.
// ---------------------------------------------------------------------------
__global__ __launch_bounds__(256) void k_proj3(
    const float* __restrict__ qi, const float* __restrict__ ki,
    const float* __restrict__ vi,
    const float* __restrict__ Wq, const float* __restrict__ Wk,
    const float* __restrict__ Wv,
    __bf16* __restrict__ qh, __bf16* __restrict__ ql_,
    __bf16* __restrict__ kh, __bf16* __restrict__ kl_,
    __bf16* __restrict__ vt)
{
  __shared__ float Ws[64][64];
  __shared__ float xs[64][68];
  int t0 = blockIdx.x * 64, hh = blockIdx.y, tid = threadIdx.x;
  const float* ins[3]  = {qi, ki, vi};
  const float* Wp[3]   = {Wq, Wk, Wv};
  #pragma unroll 1
  for (int p = 0; p < 3; p++) {
    if (p) __syncthreads();
    #pragma unroll
    for (int i = 0; i < 16; i++) {
      int idx = tid + i * 256;
      int r = idx >> 6, c = idx & 63;
      Ws[r][c] = Wp[p][idx];
      xs[c][r] = ins[p][(size_t)(t0 + r) * DEM + hh * DH + c];
    }
    __syncthreads();
    int e = tid & 63, tq = tid >> 6;
    float acc[16] = {0.f};
    for (int d = 0; d < 64; d++) {
      float w = Ws[d][e];
      float4 x0 = *(float4*)&xs[d][tq * 16 + 0];
      float4 x1 = *(float4*)&xs[d][tq * 16 + 4];
      float4 x2 = *(float4*)&xs[d][tq * 16 + 8];
      float4 x3 = *(float4*)&xs[d][tq * 16 + 12];
      acc[0]  += x0.x * w; acc[1]  += x0.y * w; acc[2]  += x0.z * w; acc[3]  += x0.w * w;
      acc[4]  += x1.x * w; acc[5]  += x1.y * w; acc[6]  += x1.z * w; acc[7]  += x1.w * w;
      acc[8]  += x2.x * w; acc[9]  += x2.y * w; acc[10] += x2.z * w; acc[11] += x2.w * w;
      acc[12] += x3.x * w; acc[13] += x3.y * w; acc[14] += x3.z * w; acc[15] += x3.w * w;
    }
    if (p == 2) {
      // V: bf16, transposed layout Vt[hh*64+e][t]
      alignas(16) __bf16 tmp[16];
      #pragma unroll
      for (int i = 0; i < 16; i++) tmp[i] = (__bf16)acc[i];
      uint4* dst = (uint4*)&vt[(size_t)(hh * DH + e) * TOK + t0 + tq * 16];
      dst[0] = ((uint4*)tmp)[0];
      dst[1] = ((uint4*)tmp)[1];
    } else {
      __bf16* ho = p ? kh : qh;
      __bf16* lo = p ? kl_ : ql_;
      #pragma unroll
      for (int i = 0; i < 16; i++) {
        float v = acc[i];
        __bf16 hv = (__bf16)v;
        size_t idx = (size_t)(t0 + tq * 16 + i) * DEM + hh * DH + e;
        ho[idx] = hv;
        lo[idx] = (__bf16)(v - (float)hv);
      }
    }
  }
}

// ---------------------------------------------------------------------------
// MFMA flash attention. Split-bf16 (hi/lo) QK^T: 3 mfma terms -> fp32-level
// scores; PV = (Phi+Plo) x Vbf16: 2 mfma terms. Online softmax in fp32.
// Quirk preserved: masked scores are 1e-19, all key tiles processed.
// Block: 64 q-rows for one (b,h); 4 waves, wave w owns q rows w*16..w*16+15.
// LDS planes XOR-swizzled; staged via global_load_lds with pre-swizzled
// global source (rule #21: linear dest + inverse-swizzled source).
// ---------------------------------------------------------------------------
__global__ __launch_bounds__(256) void k_attn_mfma(
    const __bf16* __restrict__ qh, const __bf16* __restrict__ ql,
    const __bf16* __restrict__ kh, const __bf16* __restrict__ kl,
    const __bf16* __restrict__ vt, float* __restrict__ out, int causal)
{
  __shared__ __bf16 khs[64 * 64];
  __shared__ __bf16 kls[64 * 64];
  __shared__ __bf16 vts[64 * 64];               // V^T tile: [d][kk]
  __shared__ __bf16 phs[4][16 * 64];            // per-wave P hi  [qr][kk]
  __shared__ __bf16 pls[4][16 * 64];            // per-wave P lo

  // XCD-chunked remap (nwg = 512, %8==0 -> bijective): same (b,h) stays on
  // one XCD so its 384 KB K/V panel is L2-resident.
  int lin = (blockIdx.z * gridDim.y + blockIdx.y) * gridDim.x + blockIdx.x;
  int lin2 = (lin & 7) * 64 + (lin >> 3);
  int qt = lin2 & 15, h = (lin2 >> 4) & 15, b = lin2 >> 8;

  int tid = threadIdx.x, lane = tid & 63, w = tid >> 6;
  int fr = lane & 15, fkg = lane >> 4;
  int q0 = qt * 64;

  // Q fragments straight from global (fixed across k-tiles)
  const __bf16* qhb = qh + ((size_t)(b * SEQ + q0 + w * 16 + fr)) * DEM + h * DH;
  const __bf16* qlb = ql + ((size_t)(b * SEQ + q0 + w * 16 + fr)) * DEM + h * DH;
  bf16x8 qf0 = *(const bf16x8*)(qhb + fkg * 8);
  bf16x8 qf1 = *(const bf16x8*)(qhb + fkg * 8 + 32);
  bf16x8 qg0 = *(const bf16x8*)(qlb + fkg * 8);
  bf16x8 qg1 = *(const bf16x8*)(qlb + fkg * 8 + 32);

  const __bf16* khb = kh + ((size_t)b * SEQ) * DEM + h * DH;
  const __bf16* klb = kl + ((size_t)b * SEQ) * DEM + h * DH;
  const __bf16* vtb = vt + (size_t)(h * DH) * TOK + b * SEQ;

  float m[4], l[4] = {0.f, 0.f, 0.f, 0.f};
  m[0] = m[1] = m[2] = m[3] = -INFINITY;
  f32x4 o[4] = {};
  int qrow_g = q0 + w * 16;

  for (int kt = 0; kt < 16; kt++) {
    if (kt) __syncthreads();
    #pragma unroll
    for (int i = 0; i < 2; i++) {
      int cid = tid + i * 256;          // 16B chunk id within 64x64 tile
      int r = cid >> 3, cc = cid & 7;
      int sc = ((cc ^ (r & 7)) << 3);   // inverse-swizzled source col (elems)
      __builtin_amdgcn_global_load_lds(
          (gvoid_t*)(khb + (size_t)(kt * 64 + r) * DEM + sc),
          (lvoid_t*)(khs + cid * 8), 16, 0, 0);
      __builtin_amdgcn_global_load_lds(
          (gvoid_t*)(klb + (size_t)(kt * 64 + r) * DEM + sc),
          (lvoid_t*)(kls + cid * 8), 16, 0, 0);
      __builtin_amdgcn_global_load_lds(
          (gvoid_t*)(vtb + (size_t)r * TOK + kt * 64 + sc),
          (lvoid_t*)(vts + cid * 8), 16, 0, 0);
    }
    __syncthreads();

    // ---- QK^T (3-term split bf16): C rows=q (lane>>4 *4+reg), cols=kk (lane&15)
    f32x4 s[4] = {};
    #pragma unroll
    for (int j = 0; j < 4; j++) {
      int r0 = j * 16 + fr;
      bf16x8 a0 = *(const bf16x8*)(khs + swz8(r0, fkg * 8));
      bf16x8 a1 = *(const bf16x8*)(khs + swz8(r0, fkg * 8 + 32));
      bf16x8 b0 = *(const bf16x8*)(kls + swz8(r0, fkg * 8));
      bf16x8 b1 = *(const bf16x8*)(kls + swz8(r0, fkg * 8 + 32));
      s[j] = __builtin_amdgcn_mfma_f32_16x16x32_bf16(qf0, a0, s[j], 0, 0, 0);
      s[j] = __builtin_amdgcn_mfma_f32_16x16x32_bf16(qf1, a1, s[j], 0, 0, 0);
      s[j] = __builtin_amdgcn_mfma_f32_16x16x32_bf16(qf0, b0, s[j], 0, 0, 0);
      s[j] = __builtin_amdgcn_mfma_f32_16x16x32_bf16(qf1, b1, s[j], 0, 0, 0);
      s[j] = __builtin_amdgcn_mfma_f32_16x16x32_bf16(qg0, a0, s[j], 0, 0, 0);
      s[j] = __builtin_amdgcn_mfma_f32_16x16x32_bf16(qg1, a1, s[j], 0, 0, 0);
    }

    // ---- online softmax per q-row; lanes sharing a row differ only in low 4 bits
    #pragma unroll
    for (int r = 0; r < 4; r++) {
      int qg = qrow_g + fkg * 4 + r;
      float sv[4];
      #pragma unroll
      for (int j = 0; j < 4; j++) {
        float x = s[j][r] * 0.125f;
        int kg = kt * 64 + j * 16 + fr;
        if (causal && kg > qg) x = 1e-19f;
        sv[j] = x;
      }
      float tmax = fmaxf(fmaxf(sv[0], sv[1]), fmaxf(sv[2], sv[3]));
      tmax = fmaxf(tmax, __shfl_xor(tmax, 1));
      tmax = fmaxf(tmax, __shfl_xor(tmax, 2));
      tmax = fmaxf(tmax, __shfl_xor(tmax, 4));
      tmax = fmaxf(tmax, __shfl_xor(tmax, 8));
      float mnew = fmaxf(m[r], tmax);
      float alpha = __expf(m[r] - mnew);
      float p0 = __expf(sv[0] - mnew), p1 = __expf(sv[1] - mnew);
      float p2 = __expf(sv[2] - mnew), p3 = __expf(sv[3] - mnew);
      float rs = p0 + p1 + p2 + p3;
      rs += __shfl_xor(rs, 1); rs += __shfl_xor(rs, 2);
      rs += __shfl_xor(rs, 4); rs += __shfl_xor(rs, 8);
      l[r] = l[r] * alpha + rs;
      m[r] = mnew;
      #pragma unroll
      for (int jd = 0; jd < 4; jd++) o[jd][r] *= alpha;
      // P hi/lo into wave-private LDS (C-layout write, swizzled)
      int prow = fkg * 4 + r;
      float pv[4] = {p0, p1, p2, p3};
      #pragma unroll
      for (int j = 0; j < 4; j++) {
        int pcol = j * 16 + fr;
        int idx = prow * 64 + (((((pcol >> 3) ^ (prow & 7)) << 3)) | (pcol & 7));
        __bf16 hv = (__bf16)pv[j];
        phs[w][idx] = hv;
        pls[w][idx] = (__bf16)(pv[j] - (float)hv);
      }
    }

    // ---- PV: O[q][d] += (Phi+Plo) @ Vt^T. A rows=q=lane&15 (wave-private ps).
    bf16x8 pa0 = *(const bf16x8*)(&phs[w][swz8(fr, fkg * 8)]);
    bf16x8 pa1 = *(const bf16x8*)(&phs[w][swz8(fr, fkg * 8 + 32)]);
    bf16x8 pb0 = *(const bf16x8*)(&pls[w][swz8(fr, fkg * 8)]);
    bf16x8 pb1 = *(const bf16x8*)(&pls[w][swz8(fr, fkg * 8 + 32)]);
    #pragma unroll
    for (int jd = 0; jd < 4; jd++) {
      int vr0 = jd * 16 + fr;
      bf16x8 v0 = *(const bf16x8*)(vts + swz8(vr0, fkg * 8));
      bf16x8 v1 = *(const bf16x8*)(vts + swz8(vr0, fkg * 8 + 32));
      o[jd] = __builtin_amdgcn_mfma_f32_16x16x32_bf16(pa0, v0, o[jd], 0, 0, 0);
      o[jd] = __builtin_amdgcn_mfma_f32_16x16x32_bf16(pa1, v1, o[jd], 0, 0, 0);
      o[jd] = __builtin_amdgcn_mfma_f32_16x16x32_bf16(pb0, v0, o[jd], 0, 0, 0);
      o[jd] = __builtin_amdgcn_mfma_f32_16x16x32_bf16(pb1, v1, o[jd], 0, 0, 0);
    }
  }

  #pragma unroll
  for (int r = 0; r < 4; r++) {
    float inv = 1.0f / l[r];
    size_t row = (size_t)(b * SEQ + q0 + w * 16 + fkg * 4 + r);
    #pragma unroll
    for (int jd = 0; jd < 4; jd++)
      out[row * DEM + h * DH + jd * 16 + fr] = o[jd][r] * inv;
  }
}

// ---------------------------------------------------------------------------
// out = LayerNorm(a + r)*g + bb, plus optional bf16 duplicate of out.
// ---------------------------------------------------------------------------
__global__ __launch_bounds__(256) void k_addln(const float* __restrict__ a,
    const float* __restrict__ r, const float* __restrict__ g,
    const float* __restrict__ bb, float* __restrict__ out,
    __bf16* __restrict__ obf)
{
  int t = blockIdx.x, tid = threadIdx.x;
  size_t base = (size_t)t * DEM + tid * 4;
  float4 av = *(const float4*)&a[base];
  float4 rv = *(const float4*)&r[base];
  float x0 = av.x + rv.x, x1 = av.y + rv.y, x2 = av.z + rv.z, x3 = av.w + rv.w;
  float s = x0 + x1 + x2 + x3;
  float qq = x0 * x0 + x1 * x1 + x2 * x2 + x3 * x3;
  #pragma unroll
  for (int msk = 32; msk; msk >>= 1) {
    s  += __shfl_xor(s, msk);
    qq += __shfl_xor(qq, msk);
  }
  __shared__ float red[8];
  if ((tid & 63) == 0) { red[tid >> 6] = s; red[4 + (tid >> 6)] = qq; }
  __syncthreads();
  s  = red[0] + red[1] + red[2] + red[3];
  qq = red[4] + red[5] + red[6] + red[7];
  float mu = s * (1.0f / DEM);
  float var = qq * (1.0f / DEM) - mu * mu;
  float rstd = rsqrtf(var + 1e-5f);
  float4 gv = *(const float4*)&g[tid * 4];
  float4 bv = *(const float4*)&bb[tid * 4];
  float4 ov;
  ov.x = (x0 - mu) * rstd * gv.x + bv.x;
  ov.y = (x1 - mu) * rstd * gv.y + bv.y;
  ov.z = (x2 - mu) * rstd * gv.z + bv.z;
  ov.w = (x3 - mu) * rstd * gv.w + bv.w;
  *(float4*)&out[base] = ov;
  if (obf) {
    __bf16 tb[4] = {(__bf16)ov.x, (__bf16)ov.y, (__bf16)ov.z, (__bf16)ov.w};
    *(uint2*)&obf[base] = *(uint2*)tb;
  }
}

// ---------------------------------------------------------------------------
// Transpose-convert: W[K][N] fp32  ->  Wt[N][K] bf16. 64x64 tiles.
// ---------------------------------------------------------------------------
__global__ __launch_bounds__(256) void k_cvt_t(const float* __restrict__ W,
    __bf16* __restrict__ Wt, int K, int N)
{
  __shared__ float t[64][65];
  int n0 = blockIdx.x * 64, k0 = blockIdx.y * 64;
  int tid = threadIdx.x;
  int c = (tid & 15) * 4, r = tid >> 4;
  #pragma unroll
  for (int i = 0; i < 4; i++) {
    float4 v = *(const float4*)&W[(size_t)(k0 + r + i * 16) * N + n0 + c];
    t[r + i * 16][c] = v.x; t[r + i * 16][c + 1] = v.y;
    t[r + i * 16][c + 2] = v.z; t[r + i * 16][c + 3] = v.w;
  }
  __syncthreads();
  int row = tid >> 2, ko = (tid & 3) * 16;
  alignas(16) __bf16 tmp[16];
  #pragma unroll
  for (int j = 0; j < 16; j++) tmp[j] = (__bf16)t[ko + j][row];
  uint4* dst = (uint4*)&Wt[(size_t)(n0 + row) * K + k0 + ko];
  dst[0] = ((uint4*)tmp)[0];
  dst[1] = ((uint4*)tmp)[1];
}

// ---------------------------------------------------------------------------
// bf16 MFMA GEMM (m97 structure): C[M,N] = A[M,K] @ Bt[N,K]^T + bias.
// 128x128 tile, BK=32. XCD-chunked block swizzle (all grids %8==0) so the
// 16 m-tiles sharing one B-panel stay on one XCD's L2.
// ---------------------------------------------------------------------------
template <int OUT_BF, int RELU>
__global__ __launch_bounds__(256) void k_gemm_bf(
    const __bf16* __restrict__ A, const __bf16* __restrict__ Bt,
    const float* __restrict__ bias, void* __restrict__ Cout,
    int M, int N, int K)
{
  __shared__ __bf16 As[128 * 32];
  __shared__ __bf16 Bs[128 * 32];
  int tid = threadIdx.x;
  int gx = gridDim.x;
  int nwg = gx * gridDim.y;
  int lin = blockIdx.y * gx + blockIdx.x;
  if ((nwg & 7) == 0) {
    int cpx = nwg >> 3;
    lin = (lin & 7) * cpx + (lin >> 3);
  }
  int m0 = (lin % gx) * 128, n0 = (lin / gx) * 128;
  const __bf16* Ab = A + (size_t)m0 * K;
  const __bf16* Bb = Bt + (size_t)n0 * K;
  int lane = tid & 63, wave = tid >> 6;
  int wm = (wave >> 1) * 64, wn = (wave & 1) * 64;
  int fr = lane & 15;
  int fk = (lane >> 4) * 8;
  f32x4 acc[4][4] = {};

  const __bf16* Ald = As + (wm + fr) * 32 + fk;
  const __bf16* Bld = Bs + (wn + fr) * 32 + fk;

  for (int kt = 0; kt < K; kt += 32) {
    __syncthreads();
    #pragma unroll
    for (int i = 0; i < 2; i++) {
      int idx = tid + i * 256;
      int row = idx >> 2, ko = (idx & 3) * 8;
      __builtin_amdgcn_global_load_lds(
          (gvoid_t*)(Ab + (size_t)row * K + kt + ko),
          (lvoid_t*)(As + idx * 8), 16, 0, 0);
      __builtin_amdgcn_global_load_lds(
          (gvoid_t*)(Bb + (size_t)row * K + kt + ko),
          (lvoid_t*)(Bs + idx * 8), 16, 0, 0);
    }
    __syncthreads();
    bf16x8 af[4], bfr[4];
    #pragma unroll
    for (int i = 0; i < 4; i++) af[i]  = *(const bf16x8*)(Ald + i * 16 * 32);
    #pragma unroll
    for (int j = 0; j < 4; j++) bfr[j] = *(const bf16x8*)(Bld + j * 16 * 32);
    #pragma unroll
    for (int i = 0; i < 4; i++)
      #pragma unroll
      for (int j = 0; j < 4; j++)
        acc[i][j] = __builtin_amdgcn_mfma_f32_16x16x32_bf16(
            af[i], bfr[j], acc[i][j], 0, 0, 0);
  }
  int orow = (lane >> 4) * 4, ocol = lane & 15;
  #pragma unroll
  for (int i = 0; i < 4; i++) {
    #pragma unroll
    for (int j = 0; j < 4; j++) {
      int col = n0 + wn + j * 16 + ocol;
      float bsv = bias[col];
      #pragma unroll
      for (int r = 0; r < 4; r++) {
        size_t row = (size_t)(m0 + wm + i * 16 + orow + r);
        float u = acc[i][j][r] + bsv;
        if (RELU) u = fmaxf(u, 0.f);
        if (OUT_BF) ((__bf16*)Cout)[row * N + col] = (__bf16)u;
        else        ((float*)Cout)[row * N + col] = u;
      }
    }
  }
}

// ---------------------------------------------------------------------------
extern "C" void kernel_launch(void* const* d_in, const int* in_sizes, int n_in,
                              void* d_out, int out_size, void* d_ws, size_t ws_size,
                              hipStream_t stream) {
  const int*   ids   = (const int*)  d_in[0];
  const float* enc_k = (const float*)d_in[1];
  const float* enc_v = (const float*)d_in[2];
  const float* emb   = (const float*)d_in[3];
  const float* Wq_m  = (const float*)d_in[4];
  const float* Wk_m  = (const float*)d_in[5];
  const float* Wv_m  = (const float*)d_in[6];
  const float* Wq_c  = (const float*)d_in[7];
  const float* Wk_c  = (const float*)d_in[8];
  const float* Wv_c  = (const float*)d_in[9];
  const float* ln1_g = (const float*)d_in[10];
  const float* ln1_b = (const float*)d_in[11];
  const float* ln2_g = (const float*)d_in[12];
  const float* ln2_b = (const float*)d_in[13];
  const float* ln3_g = (const float*)d_in[14];
  const float* ln3_b = (const float*)d_in[15];
  const float* W1    = (const float*)d_in[16];
  const float* b1    = (const float*)d_in[17];
  const float* W2    = (const float*)d_in[18];
  const float* b2    = (const float*)d_in[19];
  const float* Wout  = (const float*)d_in[20];
  const float* bout  = (const float*)d_in[21];
  float* out = (float*)d_out;

  // ws layout: 6 fp32 TD buffers | abf bf16 TD | w1t | w2t | woutt
  // qb region: q hi/lo bf16 planes; kb: k hi/lo; vb: Vt bf16 (half used).
  const size_t TD = (size_t)TOK * DEM;
  float* ws = (float*)d_ws;
  float* x  = ws;
  float* h  = ws + TD;
  float* op = ws + 2 * TD;
  float* qb = ws + 3 * TD;
  float* kb = ws + 4 * TD;
  float* vb = ws + 5 * TD;
  __bf16* ffb   = (__bf16*)qb;                 // TOK*FFD bf16 == qb+kb exactly
  __bf16* abf   = (__bf16*)(ws + 6 * TD);      // TD bf16
  __bf16* w1t   = abf + TD;                    // FFD*DEM
  __bf16* w2t   = w1t + (size_t)FFD * DEM;     // DEM*FFD
  __bf16* woutt = w2t + (size_t)FFD * DEM;     // VOC*DEM

  __bf16* qhb = (__bf16*)qb;  __bf16* qlb = qhb + TD;
  __bf16* khb = (__bf16*)kb;  __bf16* klb = khb + TD;
  __bf16* vtb = (__bf16*)vb;

  dim3 blk(256);
  dim3 gproj(TOK / 64, NH);
  dim3 gattn(SEQ / 64, NH, NB);

  k_embed<<<TOK, blk, 0, stream>>>(ids, emb, x);
  k_cvt_t<<<dim3(VOC / 64, DEM / 64), blk, 0, stream>>>(Wout, woutt, DEM, VOC);

  for (int l = 0; l < NL; l++) {
    const size_t wofs = (size_t)l * DH * DH;
    const size_t lofs = (size_t)l * DEM;
    // ---- masked self-attention
    k_proj3<<<gproj, blk, 0, stream>>>(x, x, x,
        Wq_m + wofs, Wk_m + wofs, Wv_m + wofs, qhb, qlb, khb, klb, vtb);
    k_attn_mfma<<<gattn, blk, 0, stream>>>(qhb, qlb, khb, klb, vtb, op, 1);
    k_addln<<<TOK, blk, 0, stream>>>(op, x, ln1_g + lofs, ln1_b + lofs, h, nullptr);
    // ---- cross-attention
    k_proj3<<<gproj, blk, 0, stream>>>(h, enc_k, enc_v,
        Wq_c + wofs, Wk_c + wofs, Wv_c + wofs, qhb, qlb, khb, klb, vtb);
    k_attn_mfma<<<gattn, blk, 0, stream>>>(qhb, qlb, khb, klb, vtb, op, 0);
    k_addln<<<TOK, blk, 0, stream>>>(op, h, ln2_g + lofs, ln2_b + lofs, h, abf);
    // ---- FFN (bf16 MFMA)
    k_cvt_t<<<dim3(FFD / 64, DEM / 64), blk, 0, stream>>>(
        W1 + (size_t)l * DEM * FFD, w1t, DEM, FFD);
    k_cvt_t<<<dim3(DEM / 64, FFD / 64), blk, 0, stream>>>(
        W2 + (size_t)l * FFD * DEM, w2t, FFD, DEM);
    k_gemm_bf<1, 1><<<dim3(TOK / 128, FFD / 128), blk, 0, stream>>>(
        abf, w1t, b1 + (size_t)l * FFD, (void*)ffb, TOK, FFD, DEM);
    k_gemm_bf<0, 0><<<dim3(TOK / 128, DEM / 128), blk, 0, stream>>>(
        ffb, w2t, b2 + lofs, (void*)op, TOK, DEM, FFD);
    k_addln<<<TOK, blk, 0, stream>>>(op, h, ln3_g + lofs, ln3_b + lofs, x, abf);
  }
  // ---- output projection (A = abf from last ln3)
  k_gemm_bf<0, 0><<<dim3(TOK / 128, VOC / 128), blk, 0, stream>>>(
      abf, woutt, bout, (void*)out, TOK, VOC, DEM);
}

// Round 2
// 2721.987 us; speedup vs baseline: 1.5074x; 1.0205x over previous
//
#include <hip/hip_runtime.h>
#include <math.h>

#define NB   2
#define SEQ  1024
#define TOK  2048      // NB*SEQ
#define DEM  1024
#define NH   16
#define DH   64
#define FFD  4096
#define NL   6
#define VOC  32000

typedef __bf16 bf16x8 __attribute__((ext_vector_type(8)));
typedef float  f32x4  __attribute__((ext_vector_type(4)));
typedef const __attribute__((address_space(1))) void gvoid_t;
typedef __attribute__((address_space(3)))       void lvoid_t;

// XOR-swizzle for [R][64] bf16 LDS planes, 16B-chunk granularity.
__device__ __forceinline__ int swz8(int r, int c8) {
  return r * 64 + (((c8 >> 3) ^ (r & 7)) << 3);
}

// ---------------------------------------------------------------------------
// Embedding + positional encoding: x[t,i] = emb[ids[t],i]*32 + pe(s,i)
// ---------------------------------------------------------------------------
__global__ __launch_bounds__(256) void k_embed(const int* __restrict__ ids,
    const float* __restrict__ emb, float* __restrict__ x)
{
  int t = blockIdx.x;
  int s = t & (SEQ - 1);
  int id = ids[t];
  int d0 = threadIdx.x * 4;
  const float ln10000 = 9.210340371976184f;
  #pragma unroll
  for (int j = 0; j < 4; j++) {
    int i = d0 + j;
    float inv = expf(-(2.0f * (float)i / (float)DEM) * ln10000);
    float ang = (float)s * inv;
    float pe = ((i & 1) == 0) ? sinf(ang) : cosf(ang);
    x[(size_t)t * DEM + i] = emb[(size_t)id * DEM + i] * 32.0f + pe;
  }
}

// ---------------------------------------------------------------------------
// Fused q/k/v per-head projection (3 phases through shared LDS, 1 dispatch).
// q,k outputs: bf16 hi/lo planes [TOK][DEM] (split-bf16 for exact-ish QK^T).
// v output: bf16, TRANSPOSED to Vt[DEM][TOK] so attention PV stages linearly.
// ---------------------------------------------------------------------------
__global__ __launch_bounds__(256) void k_proj3(
    const float* __restrict__ qi, const float* __restrict__ ki,
    const float* __restrict__ vi,
    const float* __restrict__ Wq, const float* __restrict__ Wk,
    const float* __restrict__ Wv,
    __bf16* __restrict__ qh, __bf16* __restrict__ ql_,
    __bf16* __restrict__ kh, __bf16* __restrict__ kl_,
    __bf16* __restrict__ vt)
{
  __shared__ float Ws[64][64];
  __shared__ float xs[64][68];
  int t0 = blockIdx.x * 64, hh = blockIdx.y, tid = threadIdx.x;
  const float* ins[3]  = {qi, ki, vi};
  const float* Wp[3]   = {Wq, Wk, Wv};
  #pragma unroll 1
  for (int p = 0; p < 3; p++) {
    if (p) __syncthreads();
    #pragma unroll
    for (int i = 0; i < 16; i++) {
      int idx = tid + i * 256;
      int r = idx >> 6, c = idx & 63;
      Ws[r][c] = Wp[p][idx];
      xs[c][r] = ins[p][(size_t)(t0 + r) * DEM + hh * DH + c];
    }
    __syncthreads();
    int e = tid & 63, tq = tid >> 6;
    float acc[16] = {0.f};
    for (int d = 0; d < 64; d++) {
      float w = Ws[d][e];
      float4 x0 = *(float4*)&xs[d][tq * 16 + 0];
      float4 x1 = *(float4*)&xs[d][tq * 16 + 4];
      float4 x2 = *(float4*)&xs[d][tq * 16 + 8];
      float4 x3 = *(float4*)&xs[d][tq * 16 + 12];
      acc[0]  += x0.x * w; acc[1]  += x0.y * w; acc[2]  += x0.z * w; acc[3]  += x0.w * w;
      acc[4]  += x1.x * w; acc[5]  += x1.y * w; acc[6]  += x1.z * w; acc[7]  += x1.w * w;
      acc[8]  += x2.x * w; acc[9]  += x2.y * w; acc[10] += x2.z * w; acc[11] += x2.w * w;
      acc[12] += x3.x * w; acc[13] += x3.y * w; acc[14] += x3.z * w; acc[15] += x3.w * w;
    }
    if (p == 2) {
      alignas(16) __bf16 tmp[16];
      #pragma unroll
      for (int i = 0; i < 16; i++) tmp[i] = (__bf16)acc[i];
      uint4* dst = (uint4*)&vt[(size_t)(hh * DH + e) * TOK + t0 + tq * 16];
      dst[0] = ((uint4*)tmp)[0];
      dst[1] = ((uint4*)tmp)[1];
    } else {
      __bf16* ho = p ? kh : qh;
      __bf16* lo = p ? kl_ : ql_;
      #pragma unroll
      for (int i = 0; i < 16; i++) {
        float v = acc[i];
        __bf16 hv = (__bf16)v;
        size_t idx = (size_t)(t0 + tq * 16 + i) * DEM + hh * DH + e;
        ho[idx] = hv;
        lo[idx] = (__bf16)(v - (float)hv);
      }
    }
  }
}

// ---------------------------------------------------------------------------
// MFMA flash attention, 2-phase double-buffered staging (counted vmcnt, raw
// barriers). Split-bf16 QK^T (3 terms); PV = P_hi x Vbf16 (V's own bf16
// rounding is the error floor, so a P-lo term buys nothing).
// Quirk preserved: masked scores are 1e-19, all key tiles processed.
// ---------------------------------------------------------------------------
__global__ __launch_bounds__(256) void k_attn_mfma(
    const __bf16* __restrict__ qh, const __bf16* __restrict__ ql,
    const __bf16* __restrict__ kh, const __bf16* __restrict__ kl,
    const __bf16* __restrict__ vt, float* __restrict__ out, int causal)
{
  __shared__ __bf16 khs[2][64 * 64];
  __shared__ __bf16 kls[2][64 * 64];
  __shared__ __bf16 vts[2][64 * 64];            // V^T tile: [d][kk]
  __shared__ __bf16 phs[4][16 * 64];            // per-wave P hi  [qr][kk]

  // XCD-chunked remap (nwg = 512, %8==0 -> bijective)
  int lin = (blockIdx.z * gridDim.y + blockIdx.y) * gridDim.x + blockIdx.x;
  int lin2 = (lin & 7) * 64 + (lin >> 3);
  int qt = lin2 & 15, h = (lin2 >> 4) & 15, b = lin2 >> 8;

  int tid = threadIdx.x, lane = tid & 63, w = tid >> 6;
  int fr = lane & 15, fkg = lane >> 4;
  int q0 = qt * 64;

  const __bf16* qhb = qh + ((size_t)(b * SEQ + q0 + w * 16 + fr)) * DEM + h * DH;
  const __bf16* qlb = ql + ((size_t)(b * SEQ + q0 + w * 16 + fr)) * DEM + h * DH;
  bf16x8 qf0 = *(const bf16x8*)(qhb + fkg * 8);
  bf16x8 qf1 = *(const bf16x8*)(qhb + fkg * 8 + 32);
  bf16x8 qg0 = *(const bf16x8*)(qlb + fkg * 8);
  bf16x8 qg1 = *(const bf16x8*)(qlb + fkg * 8 + 32);

  const __bf16* khb = kh + ((size_t)b * SEQ) * DEM + h * DH;
  const __bf16* klb = kl + ((size_t)b * SEQ) * DEM + h * DH;
  const __bf16* vtb = vt + (size_t)(h * DH) * TOK + b * SEQ;

  // stage one 64x64 k-tile (K hi, K lo, V^T) into buffer `buf`
  auto STAGE = [&](int buf, int kt) {
    #pragma unroll
    for (int i = 0; i < 2; i++) {
      int cid = tid + i * 256;          // 16B chunk id within 64x64 tile
      int r = cid >> 3, cc = cid & 7;
      int sc = ((cc ^ (r & 7)) << 3);   // inverse-swizzled source col
      __builtin_amdgcn_global_load_lds(
          (gvoid_t*)(khb + (size_t)(kt * 64 + r) * DEM + sc),
          (lvoid_t*)(&khs[buf][cid * 8]), 16, 0, 0);
      __builtin_amdgcn_global_load_lds(
          (gvoid_t*)(klb + (size_t)(kt * 64 + r) * DEM + sc),
          (lvoid_t*)(&kls[buf][cid * 8]), 16, 0, 0);
      __builtin_amdgcn_global_load_lds(
          (gvoid_t*)(vtb + (size_t)r * TOK + kt * 64 + sc),
          (lvoid_t*)(&vts[buf][cid * 8]), 16, 0, 0);
    }
  };

  float m[4], l[4] = {0.f, 0.f, 0.f, 0.f};
  m[0] = m[1] = m[2] = m[3] = -INFINITY;
  f32x4 o[4] = {};
  int qrow_g = q0 + w * 16;

  STAGE(0, 0);

  for (int kt = 0; kt < 16; kt++) {
    int cur = kt & 1;
    if (kt < 15) {
      STAGE(cur ^ 1, kt + 1);           // prefetch next tile (stays in flight)
      asm volatile("s_waitcnt vmcnt(6)" ::: "memory");
    } else {
      asm volatile("s_waitcnt vmcnt(0)" ::: "memory");
    }
    __builtin_amdgcn_s_barrier();       // all waves' current-tile loads landed

    // ---- QK^T (3-term split bf16)
    f32x4 s[4] = {};
    __builtin_amdgcn_s_setprio(1);
    #pragma unroll
    for (int j = 0; j < 4; j++) {
      int r0 = j * 16 + fr;
      bf16x8 a0 = *(const bf16x8*)(&khs[cur][swz8(r0, fkg * 8)]);
      bf16x8 a1 = *(const bf16x8*)(&khs[cur][swz8(r0, fkg * 8 + 32)]);
      bf16x8 b0 = *(const bf16x8*)(&kls[cur][swz8(r0, fkg * 8)]);
      bf16x8 b1 = *(const bf16x8*)(&kls[cur][swz8(r0, fkg * 8 + 32)]);
      s[j] = __builtin_amdgcn_mfma_f32_16x16x32_bf16(qf0, a0, s[j], 0, 0, 0);
      s[j] = __builtin_amdgcn_mfma_f32_16x16x32_bf16(qf1, a1, s[j], 0, 0, 0);
      s[j] = __builtin_amdgcn_mfma_f32_16x16x32_bf16(qf0, b0, s[j], 0, 0, 0);
      s[j] = __builtin_amdgcn_mfma_f32_16x16x32_bf16(qf1, b1, s[j], 0, 0, 0);
      s[j] = __builtin_amdgcn_mfma_f32_16x16x32_bf16(qg0, a0, s[j], 0, 0, 0);
      s[j] = __builtin_amdgcn_mfma_f32_16x16x32_bf16(qg1, a1, s[j], 0, 0, 0);
    }
    __builtin_amdgcn_s_setprio(0);

    // ---- online softmax per q-row
    #pragma unroll
    for (int r = 0; r < 4; r++) {
      int qg = qrow_g + fkg * 4 + r;
      float sv[4];
      #pragma unroll
      for (int j = 0; j < 4; j++) {
        float x = s[j][r] * 0.125f;
        int kg = kt * 64 + j * 16 + fr;
        if (causal && kg > qg) x = 1e-19f;
        sv[j] = x;
      }
      float tmax = fmaxf(fmaxf(sv[0], sv[1]), fmaxf(sv[2], sv[3]));
      tmax = fmaxf(tmax, __shfl_xor(tmax, 1));
      tmax = fmaxf(tmax, __shfl_xor(tmax, 2));
      tmax = fmaxf(tmax, __shfl_xor(tmax, 4));
      tmax = fmaxf(tmax, __shfl_xor(tmax, 8));
      float mnew = fmaxf(m[r], tmax);
      float alpha = __expf(m[r] - mnew);
      float p0 = __expf(sv[0] - mnew), p1 = __expf(sv[1] - mnew);
      float p2 = __expf(sv[2] - mnew), p3 = __expf(sv[3] - mnew);
      float rs = p0 + p1 + p2 + p3;
      rs += __shfl_xor(rs, 1); rs += __shfl_xor(rs, 2);
      rs += __shfl_xor(rs, 4); rs += __shfl_xor(rs, 8);
      l[r] = l[r] * alpha + rs;
      m[r] = mnew;
      #pragma unroll
      for (int jd = 0; jd < 4; jd++) o[jd][r] *= alpha;
      // P hi into wave-private LDS (C-layout write, swizzled)
      int prow = fkg * 4 + r;
      float pv[4] = {p0, p1, p2, p3};
      #pragma unroll
      for (int j = 0; j < 4; j++) {
        int pcol = j * 16 + fr;
        int idx = prow * 64 + (((((pcol >> 3) ^ (prow & 7)) << 3)) | (pcol & 7));
        phs[w][idx] = (__bf16)pv[j];
      }
    }

    // ---- PV: O[q][d] += P_hi @ Vt^T (wave-private P, lgkm-ordered)
    bf16x8 pa0 = *(const bf16x8*)(&phs[w][swz8(fr, fkg * 8)]);
    bf16x8 pa1 = *(const bf16x8*)(&phs[w][swz8(fr, fkg * 8 + 32)]);
    __builtin_amdgcn_s_setprio(1);
    #pragma unroll
    for (int jd = 0; jd < 4; jd++) {
      int vr0 = jd * 16 + fr;
      bf16x8 v0 = *(const bf16x8*)(&vts[cur][swz8(vr0, fkg * 8)]);
      bf16x8 v1 = *(const bf16x8*)(&vts[cur][swz8(vr0, fkg * 8 + 32)]);
      o[jd] = __builtin_amdgcn_mfma_f32_16x16x32_bf16(pa0, v0, o[jd], 0, 0, 0);
      o[jd] = __builtin_amdgcn_mfma_f32_16x16x32_bf16(pa1, v1, o[jd], 0, 0, 0);
    }
    __builtin_amdgcn_s_setprio(0);
    __builtin_amdgcn_s_barrier();       // all reads of buf done before rewrite
  }

  #pragma unroll
  for (int r = 0; r < 4; r++) {
    float inv = 1.0f / l[r];
    size_t row = (size_t)(b * SEQ + q0 + w * 16 + fkg * 4 + r);
    #pragma unroll
    for (int jd = 0; jd < 4; jd++)
      out[row * DEM + h * DH + jd * 16 + fr] = o[jd][r] * inv;
  }
}

// ---------------------------------------------------------------------------
// out = LayerNorm(a + r)*g + bb, plus optional bf16 duplicate of out.
// ---------------------------------------------------------------------------
__global__ __launch_bounds__(256) void k_addln(const float* __restrict__ a,
    const float* __restrict__ r, const float* __restrict__ g,
    const float* __restrict__ bb, float* __restrict__ out,
    __bf16* __restrict__ obf)
{
  int t = blockIdx.x, tid = threadIdx.x;
  size_t base = (size_t)t * DEM + tid * 4;
  float4 av = *(const float4*)&a[base];
  float4 rv = *(const float4*)&r[base];
  float x0 = av.x + rv.x, x1 = av.y + rv.y, x2 = av.z + rv.z, x3 = av.w + rv.w;
  float s = x0 + x1 + x2 + x3;
  float qq = x0 * x0 + x1 * x1 + x2 * x2 + x3 * x3;
  #pragma unroll
  for (int msk = 32; msk; msk >>= 1) {
    s  += __shfl_xor(s, msk);
    qq += __shfl_xor(qq, msk);
  }
  __shared__ float red[8];
  if ((tid & 63) == 0) { red[tid >> 6] = s; red[4 + (tid >> 6)] = qq; }
  __syncthreads();
  s  = red[0] + red[1] + red[2] + red[3];
  qq = red[4] + red[5] + red[6] + red[7];
  float mu = s * (1.0f / DEM);
  float var = qq * (1.0f / DEM) - mu * mu;
  float rstd = rsqrtf(var + 1e-5f);
  float4 gv = *(const float4*)&g[tid * 4];
  float4 bv = *(const float4*)&bb[tid * 4];
  float4 ov;
  ov.x = (x0 - mu) * rstd * gv.x + bv.x;
  ov.y = (x1 - mu) * rstd * gv.y + bv.y;
  ov.z = (x2 - mu) * rstd * gv.z + bv.z;
  ov.w = (x3 - mu) * rstd * gv.w + bv.w;
  *(float4*)&out[base] = ov;
  if (obf) {
    __bf16 tb[4] = {(__bf16)ov.x, (__bf16)ov.y, (__bf16)ov.z, (__bf16)ov.w};
    *(uint2*)&obf[base] = *(uint2*)tb;
  }
}

// ---------------------------------------------------------------------------
// Transpose-convert: W[K][N] fp32  ->  Wt[N][K] bf16. 64x64 tiles.
// ---------------------------------------------------------------------------
__global__ __launch_bounds__(256) void k_cvt_t(const float* __restrict__ W,
    __bf16* __restrict__ Wt, int K, int N)
{
  __shared__ float t[64][65];
  int n0 = blockIdx.x * 64, k0 = blockIdx.y * 64;
  int tid = threadIdx.x;
  int c = (tid & 15) * 4, r = tid >> 4;
  #pragma unroll
  for (int i = 0; i < 4; i++) {
    float4 v = *(const float4*)&W[(size_t)(k0 + r + i * 16) * N + n0 + c];
    t[r + i * 16][c] = v.x; t[r + i * 16][c + 1] = v.y;
    t[r + i * 16][c + 2] = v.z; t[r + i * 16][c + 3] = v.w;
  }
  __syncthreads();
  int row = tid >> 2, ko = (tid & 3) * 16;
  alignas(16) __bf16 tmp[16];
  #pragma unroll
  for (int j = 0; j < 16; j++) tmp[j] = (__bf16)t[ko + j][row];
  uint4* dst = (uint4*)&Wt[(size_t)(n0 + row) * K + k0 + ko];
  dst[0] = ((uint4*)tmp)[0];
  dst[1] = ((uint4*)tmp)[1];
}

// ---------------------------------------------------------------------------
// bf16 MFMA GEMM (m97 structure): C[M,N] = A[M,K] @ Bt[N,K]^T + bias.
// ---------------------------------------------------------------------------
template <int OUT_BF, int RELU>
__global__ __launch_bounds__(256) void k_gemm_bf(
    const __bf16* __restrict__ A, const __bf16* __restrict__ Bt,
    const float* __restrict__ bias, void* __restrict__ Cout,
    int M, int N, int K)
{
  __shared__ __bf16 As[128 * 32];
  __shared__ __bf16 Bs[128 * 32];
  int tid = threadIdx.x;
  int gx = gridDim.x;
  int nwg = gx * gridDim.y;
  int lin = blockIdx.y * gx + blockIdx.x;
  if ((nwg & 7) == 0) {
    int cpx = nwg >> 3;
    lin = (lin & 7) * cpx + (lin >> 3);
  }
  int m0 = (lin % gx) * 128, n0 = (lin / gx) * 128;
  const __bf16* Ab = A + (size_t)m0 * K;
  const __bf16* Bb = Bt + (size_t)n0 * K;
  int lane = tid & 63, wave = tid >> 6;
  int wm = (wave >> 1) * 64, wn = (wave & 1) * 64;
  int fr = lane & 15;
  int fk = (lane >> 4) * 8;
  f32x4 acc[4][4] = {};

  const __bf16* Ald = As + (wm + fr) * 32 + fk;
  const __bf16* Bld = Bs + (wn + fr) * 32 + fk;

  for (int kt = 0; kt < K; kt += 32) {
    __syncthreads();
    #pragma unroll
    for (int i = 0; i < 2; i++) {
      int idx = tid + i * 256;
      int row = idx >> 2, ko = (idx & 3) * 8;
      __builtin_amdgcn_global_load_lds(
          (gvoid_t*)(Ab + (size_t)row * K + kt + ko),
          (lvoid_t*)(As + idx * 8), 16, 0, 0);
      __builtin_amdgcn_global_load_lds(
          (gvoid_t*)(Bb + (size_t)row * K + kt + ko),
          (lvoid_t*)(Bs + idx * 8), 16, 0, 0);
    }
    __syncthreads();
    bf16x8 af[4], bfr[4];
    #pragma unroll
    for (int i = 0; i < 4; i++) af[i]  = *(const bf16x8*)(Ald + i * 16 * 32);
    #pragma unroll
    for (int j = 0; j < 4; j++) bfr[j] = *(const bf16x8*)(Bld + j * 16 * 32);
    #pragma unroll
    for (int i = 0; i < 4; i++)
      #pragma unroll
      for (int j = 0; j < 4; j++)
        acc[i][j] = __builtin_amdgcn_mfma_f32_16x16x32_bf16(
            af[i], bfr[j], acc[i][j], 0, 0, 0);
  }
  int orow = (lane >> 4) * 4, ocol = lane & 15;
  #pragma unroll
  for (int i = 0; i < 4; i++) {
    #pragma unroll
    for (int j = 0; j < 4; j++) {
      int col = n0 + wn + j * 16 + ocol;
      float bsv = bias[col];
      #pragma unroll
      for (int r = 0; r < 4; r++) {
        size_t row = (size_t)(m0 + wm + i * 16 + orow + r);
        float u = acc[i][j][r] + bsv;
        if (RELU) u = fmaxf(u, 0.f);
        if (OUT_BF) ((__bf16*)Cout)[row * N + col] = (__bf16)u;
        else        ((float*)Cout)[row * N + col] = u;
      }
    }
  }
}

// ---------------------------------------------------------------------------
extern "C" void kernel_launch(void* const* d_in, const int* in_sizes, int n_in,
                              void* d_out, int out_size, void* d_ws, size_t ws_size,
                              hipStream_t stream) {
  const int*   ids   = (const int*)  d_in[0];
  const float* enc_k = (const float*)d_in[1];
  const float* enc_v = (const float*)d_in[2];
  const float* emb   = (const float*)d_in[3];
  const float* Wq_m  = (const float*)d_in[4];
  const float* Wk_m  = (const float*)d_in[5];
  const float* Wv_m  = (const float*)d_in[6];
  const float* Wq_c  = (const float*)d_in[7];
  const float* Wk_c  = (const float*)d_in[8];
  const float* Wv_c  = (const float*)d_in[9];
  const float* ln1_g = (const float*)d_in[10];
  const float* ln1_b = (const float*)d_in[11];
  const float* ln2_g = (const float*)d_in[12];
  const float* ln2_b = (const float*)d_in[13];
  const float* ln3_g = (const float*)d_in[14];
  const float* ln3_b = (const float*)d_in[15];
  const float* W1    = (const float*)d_in[16];
  const float* b1    = (const float*)d_in[17];
  const float* W2    = (const float*)d_in[18];
  const float* b2    = (const float*)d_in[19];
  const float* Wout  = (const float*)d_in[20];
  const float* bout  = (const float*)d_in[21];
  float* out = (float*)d_out;

  const size_t TD = (size_t)TOK * DEM;
  float* ws = (float*)d_ws;
  float* x  = ws;
  float* h  = ws + TD;
  float* op = ws + 2 * TD;
  float* qb = ws + 3 * TD;
  float* kb = ws + 4 * TD;
  float* vb = ws + 5 * TD;
  __bf16* ffb   = (__bf16*)qb;                 // TOK*FFD bf16 == qb+kb exactly
  __bf16* abf   = (__bf16*)(ws + 6 * TD);      // TD bf16
  __bf16* w1t   = abf + TD;                    // FFD*DEM
  __bf16* w2t   = w1t + (size_t)FFD * DEM;     // DEM*FFD
  __bf16* woutt = w2t + (size_t)FFD * DEM;     // VOC*DEM

  __bf16* qhb = (__bf16*)qb;  __bf16* qlb = qhb + TD;
  __bf16* khb = (__bf16*)kb;  __bf16* klb = khb + TD;
  __bf16* vtb = (__bf16*)vb;

  dim3 blk(256);
  dim3 gproj(TOK / 64, NH);
  dim3 gattn(SEQ / 64, NH, NB);

  k_embed<<<TOK, blk, 0, stream>>>(ids, emb, x);
  k_cvt_t<<<dim3(VOC / 64, DEM / 64), blk, 0, stream>>>(Wout, woutt, DEM, VOC);

  for (int l = 0; l < NL; l++) {
    const size_t wofs = (size_t)l * DH * DH;
    const size_t lofs = (size_t)l * DEM;
    // ---- masked self-attention
    k_proj3<<<gproj, blk, 0, stream>>>(x, x, x,
        Wq_m + wofs, Wk_m + wofs, Wv_m + wofs, qhb, qlb, khb, klb, vtb);
    k_attn_mfma<<<gattn, blk, 0, stream>>>(qhb, qlb, khb, klb, vtb, op, 1);
    k_addln<<<TOK, blk, 0, stream>>>(op, x, ln1_g + lofs, ln1_b + lofs, h, nullptr);
    // ---- cross-attention
    k_proj3<<<gproj, blk, 0, stream>>>(h, enc_k, enc_v,
        Wq_c + wofs, Wk_c + wofs, Wv_c + wofs, qhb, qlb, khb, klb, vtb);
    k_attn_mfma<<<gattn, blk, 0, stream>>>(qhb, qlb, khb, klb, vtb, op, 0);
    k_addln<<<TOK, blk, 0, stream>>>(op, h, ln2_g + lofs, ln2_b + lofs, h, abf);
    // ---- FFN (bf16 MFMA)
    k_cvt_t<<<dim3(FFD / 64, DEM / 64), blk, 0, stream>>>(
        W1 + (size_t)l * DEM * FFD, w1t, DEM, FFD);
    k_cvt_t<<<dim3(DEM / 64, FFD / 64), blk, 0, stream>>>(
        W2 + (size_t)l * FFD * DEM, w2t, FFD, DEM);
    k_gemm_bf<1, 1><<<dim3(TOK / 128, FFD / 128), blk, 0, stream>>>(
        abf, w1t, b1 + (size_t)l * FFD, (void*)ffb, TOK, FFD, DEM);
    k_gemm_bf<0, 0><<<dim3(TOK / 128, DEM / 128), blk, 0, stream>>>(
        ffb, w2t, b2 + lofs, (void*)op, TOK, DEM, FFD);
    k_addln<<<TOK, blk, 0, stream>>>(op, h, ln3_g + lofs, ln3_b + lofs, x, abf);
  }
  // ---- output projection (A = abf from last ln3)
  k_gemm_bf<0, 0><<<dim3(TOK / 128, VOC / 128), blk, 0, stream>>>(
      abf, woutt, bout, (void*)out, TOK, VOC, DEM);
}